// Round 8
// baseline (160.155 us; speedup 1.0000x reference)
//
#include <hip/hip_runtime.h>
#include <hip/hip_bf16.h>

#define Bn 64
#define Cn 128
#define Tn 2048
#define Fn 5
#define Nn 640

typedef __attribute__((ext_vector_type(8))) short bf16x8;
typedef __attribute__((ext_vector_type(4))) short bf16x4;
typedef __attribute__((ext_vector_type(4))) float f32x4;

// round-to-nearest-even f32 -> bf16
__device__ __forceinline__ short f2bf(float f) {
    union { float f; unsigned u; } v; v.f = f;
    unsigned r = (v.u + 0x7fffu + ((v.u >> 16) & 1u)) >> 16;
    return (short)r;
}
__device__ __forceinline__ float bf2f(short h) {
    union { unsigned u; float f; } v; v.u = ((unsigned)(unsigned short)h) << 16;
    return v.f;
}

__device__ __forceinline__ const float* pick_band(const float* d0, const float* d1,
                                                  const float* d2, const float* d3,
                                                  const float* d4, int f) {
    return (f == 0) ? d0 : (f == 1) ? d1 : (f == 2) ? d2 : (f == 3) ? d3 : d4;
}

// ---------------- K1: pure streaming f32 -> bf16 convert ----------------
// Perfectly coalesced (wave reads 2 KB contiguous per unrolled pair).
// nontemporal input loads: f32 read once, don't pollute L3 -> the 168 MB bf16
// output stays L3-resident for K2.
#define TOT_UNITS (5u * (1u << 21))   // (5*Bn*Cn*Tn)/8 = 10485760
__global__ __launch_bounds__(256)
void k1_convert(const float* __restrict__ d0, const float* __restrict__ d1,
                const float* __restrict__ d2, const float* __restrict__ d3,
                const float* __restrict__ d4, short* __restrict__ wsb)
{
    const unsigned stride = gridDim.x * 256u;
    for (unsigned u = blockIdx.x * 256u + threadIdx.x; u < TOT_UNITS; u += stride) {
        const int band = u >> 21;                       // Bn*Cn*Tn = 2^24 elems = 2^21 units
        const size_t off = (size_t)(u & ((1u << 21) - 1)) * 8;
        const float* sp = pick_band(d0, d1, d2, d3, d4, band) + off;
        f32x4 v0 = __builtin_nontemporal_load((const f32x4*)sp);
        f32x4 v1 = __builtin_nontemporal_load((const f32x4*)(sp + 4));
        bf16x8 h;
        h[0]=f2bf(v0[0]); h[1]=f2bf(v0[1]); h[2]=f2bf(v0[2]); h[3]=f2bf(v0[3]);
        h[4]=f2bf(v1[0]); h[5]=f2bf(v1[1]); h[6]=f2bf(v1[2]); h[7]=f2bf(v1[3]);
        *(bf16x8*)(wsb + (size_t)u * 8) = h;            // normal store -> L3
    }
}

// ---------------- K2: Gram + assembly from L3-resident bf16 ----------------
#define TC2 128
#define NC2 16
#define BUF2 (Cn * TC2 * 2)   // 32 KB per buffer

// bf16 row = 256 B; XOR-swizzle rows across 16B slots (G4)
__device__ __forceinline__ int swz2(int row, int bytecol) {
    return (row * 256 + bytecol) ^ ((row & 7) << 4);
}

__global__ __launch_bounds__(512, 4)
void k2_gram(const short* __restrict__ wsb, float* __restrict__ out)
{
    __shared__ __align__(16) char smem[Cn * Cn * 4];   // 64 KB: 2x32KB bf16 dbuf; epilogue f32 A-tile
    __shared__ float S_lds[Cn], diag[Cn], mrow[Cn], ivrow[Cn], Dsum[Cn], dinv_s[Cn];

    const int tid = threadIdx.x;
    const int bfid = blockIdx.x;
    const int b = bfid / Fn;
    const int f = bfid - b * Fn;
    // ws layout: [band][b][c][t]
    const short* src = wsb + ((size_t)f * Bn + b) * (Cn * Tn);

    if (tid < Cn) { S_lds[tid] = 0.0f; Dsum[tid] = 0.0f; }

    // staging: thread covers rows (srow + 32i), 16 B (8 bf16) at segment sseg
    const int srow = tid >> 4;          // 0..31
    const int sseg = tid & 15;          // 0..15
    const short* tb0 = src + (size_t)srow * Tn + sseg * 8;

    // wave mapping: 8 waves in 4x2 grid, each owns a 32x64 tile of the Gram
    const int lane = tid & 63;
    const int w  = tid >> 6;
    const int wr = w >> 1;
    const int wc = w & 1;
    const int r0 = wr * 32;
    const int c0 = wc * 64;
    const int lg = lane >> 4;
    const int ll = lane & 15;

    f32x4 acc[2][4] = {};
    float psum[4] = {0.f, 0.f, 0.f, 0.f};
    bf16x8 pfA[4], pfB[4];

    auto issueA = [&](int ch) {
        const short* cb = tb0 + ch * TC2;
        #pragma unroll
        for (int i = 0; i < 4; ++i) pfA[i] = *(const bf16x8*)(cb + (size_t)(i * 32) * Tn);
    };
    auto issueB = [&](int ch) {
        const short* cb = tb0 + ch * TC2;
        #pragma unroll
        for (int i = 0; i < 4; ++i) pfB[i] = *(const bf16x8*)(cb + (size_t)(i * 32) * Tn);
    };
    auto convA = [&](int buf) {
        char* base = smem + buf * BUF2;
        #pragma unroll
        for (int i = 0; i < 4; ++i) {
            const int row = i * 32 + srow;
            bf16x8 hv = pfA[i];
            psum[i] += bf2f(hv[0]) + bf2f(hv[1]) + bf2f(hv[2]) + bf2f(hv[3])
                     + bf2f(hv[4]) + bf2f(hv[5]) + bf2f(hv[6]) + bf2f(hv[7]);
            *(bf16x8*)(base + swz2(row, sseg * 16)) = hv;
        }
    };
    auto convB = [&](int buf) {
        char* base = smem + buf * BUF2;
        #pragma unroll
        for (int i = 0; i < 4; ++i) {
            const int row = i * 32 + srow;
            bf16x8 hv = pfB[i];
            psum[i] += bf2f(hv[0]) + bf2f(hv[1]) + bf2f(hv[2]) + bf2f(hv[3])
                     + bf2f(hv[4]) + bf2f(hv[5]) + bf2f(hv[6]) + bf2f(hv[7]);
            *(bf16x8*)(base + swz2(row, sseg * 16)) = hv;
        }
    };
    auto mfma_phase = [&](int buf) {
        const char* base = smem + buf * BUF2;
        #pragma unroll
        for (int ks = 0; ks < 4; ++ks) {
            bf16x8 afr[2], bfr[4];
            #pragma unroll
            for (int m = 0; m < 2; ++m)
                afr[m] = *(const bf16x8*)(base + swz2(r0 + m * 16 + ll, ks * 64 + lg * 16));
            #pragma unroll
            for (int n = 0; n < 4; ++n)
                bfr[n] = *(const bf16x8*)(base + swz2(c0 + n * 16 + ll, ks * 64 + lg * 16));
            #pragma unroll
            for (int m = 0; m < 2; ++m)
                #pragma unroll
                for (int n = 0; n < 4; ++n)
                    acc[m][n] = __builtin_amdgcn_mfma_f32_16x16x32_bf16(afr[m], bfr[n], acc[m][n], 0, 0, 0);
        }
    };

    // prologue: chunk0 staged in buf0; chunk1 (B) and chunk2 (A) in flight
    issueA(0);
    issueB(1);
    convA(0);
    issueA(2);
    asm volatile("s_waitcnt lgkmcnt(0)" ::: "memory");
    __builtin_amdgcn_s_barrier();
    __builtin_amdgcn_sched_barrier(0);

    for (int k = 0; k < NC2; k += 2) {
        convB(1);
        if (k + 3 < NC2) issueB(k + 3);
        mfma_phase(0);
        asm volatile("s_waitcnt lgkmcnt(0)" ::: "memory");
        __builtin_amdgcn_s_barrier();               // raw: vmcnt lives across
        __builtin_amdgcn_sched_barrier(0);

        if (k + 2 < NC2) {
            convA(0);
            if (k + 4 < NC2) issueA(k + 4);
        }
        mfma_phase(1);
        asm volatile("s_waitcnt lgkmcnt(0)" ::: "memory");
        __builtin_amdgcn_s_barrier();
        __builtin_amdgcn_sched_barrier(0);
    }

    // ---- epilogue ----
    #pragma unroll
    for (int i = 0; i < 4; ++i)
        atomicAdd(&S_lds[i * 32 + srow], psum[i]);

    #pragma unroll
    for (int m = 0; m < 2; ++m)
      #pragma unroll
      for (int n = 0; n < 4; ++n)
        #pragma unroll
        for (int e = 0; e < 4; ++e) {
            const int row = r0 + m * 16 + lg * 4 + e;
            const int col = c0 + n * 16 + ll;
            if (row == col) diag[row] = acc[m][n][e];
        }
    __syncthreads();

    if (tid < Cn) {
        const float S  = S_lds[tid];
        const float mu = S * (1.0f / Tn);
        float var = (diag[tid] - (float)Tn * mu * mu) * (1.0f / (Tn - 1));
        var = var < 0.f ? 0.f : var;
        const float sd = sqrtf(var);
        mrow[tid]  = mu;
        ivrow[tid] = 1.0f / (sd + 1e-8f);
        const size_t ofs = (size_t)Bn * Nn * Nn;
        __builtin_nontemporal_store(var, &out[ofs + (size_t)b * Nn + f * Cn + tid]);
        __builtin_nontemporal_store(var, &out[ofs + (size_t)Bn * Nn + ((size_t)b * Cn + tid) * Fn + f]);
    }
    __syncthreads();

    // a = 0.5*(spa + |corr|) -> LDS A-tile (reuse smem); accumulate row sums
    float* At = (float*)smem;
    {
        float mi[2][4], ii[2][4], mj[4], ij[4];
        #pragma unroll
        for (int m = 0; m < 2; ++m)
          #pragma unroll
          for (int e = 0; e < 4; ++e) {
              const int row = r0 + m * 16 + lg * 4 + e;
              mi[m][e] = mrow[row];
              ii[m][e] = ivrow[row];
          }
        #pragma unroll
        for (int n = 0; n < 4; ++n) {
            const int col = c0 + n * 16 + ll;
            mj[n] = mrow[col];
            ij[n] = ivrow[col];
        }
        const float inv = 1.0f / (Tn - 1);
        #pragma unroll
        for (int m = 0; m < 2; ++m)
          #pragma unroll
          for (int e = 0; e < 4; ++e) {
              const int row = r0 + m * 16 + lg * 4 + e;
              float s = 0.f;
              #pragma unroll
              for (int n = 0; n < 4; ++n) {
                  const int col = c0 + n * 16 + ll;
                  float c = fabsf((acc[m][n][e] - (float)Tn * mi[m][e] * mj[n])
                                  * ii[m][e] * ij[n] * inv);
                  c = (row == col) ? 1.0f : c;
                  const int d = row > col ? row - col : col - row;
                  const float spa = (d >= 1 && d <= 3) ? 1.0f : 0.0f;
                  const float a = 0.5f * (spa + c);
                  At[row * Cn + col] = a;
                  s += a;
              }
              s += __shfl_xor(s, 1);
              s += __shfl_xor(s, 2);
              s += __shfl_xor(s, 4);
              s += __shfl_xor(s, 8);
              if (ll == 0) atomicAdd(&Dsum[row], s);
          }
    }
    __syncthreads();

    if (tid < Cn) dinv_s[tid] = rsqrtf(Dsum[tid] + 1e-8f);
    __syncthreads();

    // write full 128x640 stripe of A_norm (nontemporal: don't evict bf16 ws)
    float* Ob = out + (size_t)b * Nn * Nn;
    const int fc = f * Cn;
    for (int e = 0; e < 40; ++e) {
        const int idx4 = e * 2048 + tid * 4;
        const int row = idx4 / Nn;
        const int col = idx4 - row * Nn;
        const int cl = col - fc;
        f32x4 v = {0.f, 0.f, 0.f, 0.f};
        if (cl >= 0 && cl < Cn) {
            const float dr = dinv_s[row];
            v[0] = dr * At[row * Cn + cl]     * dinv_s[cl];
            v[1] = dr * At[row * Cn + cl + 1] * dinv_s[cl + 1];
            v[2] = dr * At[row * Cn + cl + 2] * dinv_s[cl + 2];
            v[3] = dr * At[row * Cn + cl + 3] * dinv_s[cl + 3];
        }
        __builtin_nontemporal_store(v, (f32x4*)(Ob + (size_t)(fc + row) * Nn + col));
    }
}

// ---------------- fallback: R5 monolith (known good, 108 us) ----------------
#define TCHUNK 64
#define NCHUNK 32
#define BUFBYTES (Cn * TCHUNK * 2)

__device__ __forceinline__ int swz(int row, int bytecol) {
    return (row * 128 + bytecol) ^ ((row & 7) << 4);
}

__global__ __launch_bounds__(512, 4)
void strg_mono(const float* __restrict__ d0, const float* __restrict__ d1,
               const float* __restrict__ d2, const float* __restrict__ d3,
               const float* __restrict__ d4, float* __restrict__ out)
{
    __shared__ __align__(16) char smem[Cn * Cn * 4];
    __shared__ float S_lds[Cn], diag[Cn], mrow[Cn], ivrow[Cn], Dsum[Cn], dinv_s[Cn];

    const int tid = threadIdx.x;
    const int bfid = blockIdx.x;
    const int b = bfid / Fn;
    const int f = bfid - b * Fn;
    const float* src = pick_band(d0, d1, d2, d3, d4, f) + (size_t)b * Cn * Tn;

    if (tid < Cn) { S_lds[tid] = 0.0f; Dsum[tid] = 0.0f; }

    const int srow = tid >> 4;
    const int sseg = tid & 15;
    const float* tb0 = src + (size_t)srow * Tn + sseg * 4;

    const int lane = tid & 63;
    const int w  = tid >> 6;
    const int wr = w >> 1;
    const int wc = w & 1;
    const int r0 = wr * 32;
    const int c0 = wc * 64;
    const int lg = lane >> 4;
    const int ll = lane & 15;

    f32x4 acc[2][4] = {};
    float psum[4] = {0.f, 0.f, 0.f, 0.f};
    float4 pfA[4], pfB[4];

    auto issueA = [&](int ch) {
        const float* cb = tb0 + ch * TCHUNK;
        #pragma unroll
        for (int i = 0; i < 4; ++i) pfA[i] = *(const float4*)(cb + (size_t)(i * 32) * Tn);
    };
    auto issueB = [&](int ch) {
        const float* cb = tb0 + ch * TCHUNK;
        #pragma unroll
        for (int i = 0; i < 4; ++i) pfB[i] = *(const float4*)(cb + (size_t)(i * 32) * Tn);
    };
    auto convA = [&](int buf) {
        char* base = smem + buf * BUFBYTES;
        #pragma unroll
        for (int i = 0; i < 4; ++i) {
            const int row = i * 32 + srow;
            float4 v = pfA[i];
            psum[i] += v.x + v.y + v.z + v.w;
            bf16x4 hh; hh[0] = f2bf(v.x); hh[1] = f2bf(v.y); hh[2] = f2bf(v.z); hh[3] = f2bf(v.w);
            *(bf16x4*)(base + swz(row, sseg * 8)) = hh;
        }
    };
    auto convB = [&](int buf) {
        char* base = smem + buf * BUFBYTES;
        #pragma unroll
        for (int i = 0; i < 4; ++i) {
            const int row = i * 32 + srow;
            float4 v = pfB[i];
            psum[i] += v.x + v.y + v.z + v.w;
            bf16x4 hh; hh[0] = f2bf(v.x); hh[1] = f2bf(v.y); hh[2] = f2bf(v.z); hh[3] = f2bf(v.w);
            *(bf16x4*)(base + swz(row, sseg * 8)) = hh;
        }
    };
    auto mfma_phase = [&](int buf) {
        const char* base = smem + buf * BUFBYTES;
        #pragma unroll
        for (int ks = 0; ks < 2; ++ks) {
            bf16x8 afr[2], bfr[4];
            #pragma unroll
            for (int m = 0; m < 2; ++m)
                afr[m] = *(const bf16x8*)(base + swz(r0 + m * 16 + ll, ks * 64 + lg * 16));
            #pragma unroll
            for (int n = 0; n < 4; ++n)
                bfr[n] = *(const bf16x8*)(base + swz(c0 + n * 16 + ll, ks * 64 + lg * 16));
            #pragma unroll
            for (int m = 0; m < 2; ++m)
                #pragma unroll
                for (int n = 0; n < 4; ++n)
                    acc[m][n] = __builtin_amdgcn_mfma_f32_16x16x32_bf16(afr[m], bfr[n], acc[m][n], 0, 0, 0);
        }
    };

    issueA(0);
    issueB(1);
    convA(0);
    issueA(2);
    asm volatile("s_waitcnt lgkmcnt(0)" ::: "memory");
    __builtin_amdgcn_s_barrier();
    __builtin_amdgcn_sched_barrier(0);

    for (int k = 0; k < NCHUNK; k += 2) {
        convB(1);
        if (k + 3 < NCHUNK) issueB(k + 3);
        mfma_phase(0);
        asm volatile("s_waitcnt lgkmcnt(0)" ::: "memory");
        __builtin_amdgcn_s_barrier();
        __builtin_amdgcn_sched_barrier(0);

        if (k + 2 < NCHUNK) {
            convA(0);
            if (k + 4 < NCHUNK) issueA(k + 4);
        }
        mfma_phase(1);
        asm volatile("s_waitcnt lgkmcnt(0)" ::: "memory");
        __builtin_amdgcn_s_barrier();
        __builtin_amdgcn_sched_barrier(0);
    }

    #pragma unroll
    for (int i = 0; i < 4; ++i)
        atomicAdd(&S_lds[i * 32 + srow], psum[i]);

    #pragma unroll
    for (int m = 0; m < 2; ++m)
      #pragma unroll
      for (int n = 0; n < 4; ++n)
        #pragma unroll
        for (int e = 0; e < 4; ++e) {
            const int row = r0 + m * 16 + lg * 4 + e;
            const int col = c0 + n * 16 + ll;
            if (row == col) diag[row] = acc[m][n][e];
        }
    __syncthreads();

    if (tid < Cn) {
        const float S  = S_lds[tid];
        const float mu = S * (1.0f / Tn);
        float var = (diag[tid] - (float)Tn * mu * mu) * (1.0f / (Tn - 1));
        var = var < 0.f ? 0.f : var;
        const float sd = sqrtf(var);
        mrow[tid]  = mu;
        ivrow[tid] = 1.0f / (sd + 1e-8f);
        const size_t ofs = (size_t)Bn * Nn * Nn;
        out[ofs + (size_t)b * Nn + f * Cn + tid] = var;
        out[ofs + (size_t)Bn * Nn + ((size_t)b * Cn + tid) * Fn + f] = var;
    }
    __syncthreads();

    float* At = (float*)smem;
    {
        float mi[2][4], ii[2][4], mj[4], ij[4];
        #pragma unroll
        for (int m = 0; m < 2; ++m)
          #pragma unroll
          for (int e = 0; e < 4; ++e) {
              const int row = r0 + m * 16 + lg * 4 + e;
              mi[m][e] = mrow[row];
              ii[m][e] = ivrow[row];
          }
        #pragma unroll
        for (int n = 0; n < 4; ++n) {
            const int col = c0 + n * 16 + ll;
            mj[n] = mrow[col];
            ij[n] = ivrow[col];
        }
        const float inv = 1.0f / (Tn - 1);
        #pragma unroll
        for (int m = 0; m < 2; ++m)
          #pragma unroll
          for (int e = 0; e < 4; ++e) {
              const int row = r0 + m * 16 + lg * 4 + e;
              float s = 0.f;
              #pragma unroll
              for (int n = 0; n < 4; ++n) {
                  const int col = c0 + n * 16 + ll;
                  float c = fabsf((acc[m][n][e] - (float)Tn * mi[m][e] * mj[n])
                                  * ii[m][e] * ij[n] * inv);
                  c = (row == col) ? 1.0f : c;
                  const int d = row > col ? row - col : col - row;
                  const float spa = (d >= 1 && d <= 3) ? 1.0f : 0.0f;
                  const float a = 0.5f * (spa + c);
                  At[row * Cn + col] = a;
                  s += a;
              }
              s += __shfl_xor(s, 1);
              s += __shfl_xor(s, 2);
              s += __shfl_xor(s, 4);
              s += __shfl_xor(s, 8);
              if (ll == 0) atomicAdd(&Dsum[row], s);
          }
    }
    __syncthreads();

    if (tid < Cn) dinv_s[tid] = rsqrtf(Dsum[tid] + 1e-8f);
    __syncthreads();

    float* Ob = out + (size_t)b * Nn * Nn;
    const int fc = f * Cn;
    for (int e = 0; e < 40; ++e) {
        const int idx4 = e * 2048 + tid * 4;
        const int row = idx4 / Nn;
        const int col = idx4 - row * Nn;
        const int cl = col - fc;
        float4 v = {0.f, 0.f, 0.f, 0.f};
        if (cl >= 0 && cl < Cn) {
            const float dr = dinv_s[row];
            v.x = dr * At[row * Cn + cl]     * dinv_s[cl];
            v.y = dr * At[row * Cn + cl + 1] * dinv_s[cl + 1];
            v.z = dr * At[row * Cn + cl + 2] * dinv_s[cl + 2];
            v.w = dr * At[row * Cn + cl + 3] * dinv_s[cl + 3];
        }
        *(float4*)(Ob + (size_t)(fc + row) * Nn + col) = v;
    }
}

extern "C" void kernel_launch(void* const* d_in, const int* in_sizes, int n_in,
                              void* d_out, int out_size, void* d_ws, size_t ws_size,
                              hipStream_t stream) {
    const float* d0 = (const float*)d_in[0];
    const float* d1 = (const float*)d_in[1];
    const float* d2 = (const float*)d_in[2];
    const float* d3 = (const float*)d_in[3];
    const float* d4 = (const float*)d_in[4];
    float* out = (float*)d_out;

    const size_t need = (size_t)5 * Bn * Cn * Tn * sizeof(short);  // 168 MB bf16
    if (ws_size >= need) {
        short* wsb = (short*)d_ws;
        k1_convert<<<dim3(2560), dim3(256), 0, stream>>>(d0, d1, d2, d3, d4, wsb);
        k2_gram<<<dim3(Bn * Fn), dim3(512), 0, stream>>>(wsb, out);
    } else {
        strg_mono<<<dim3(Bn * Fn), dim3(512), 0, stream>>>(d0, d1, d2, d3, d4, out);
    }
}

// Round 9
// 113.695 us; speedup vs baseline: 1.4086x; 1.4086x over previous
//
#include <hip/hip_runtime.h>
#include <hip/hip_bf16.h>

#define Bn 64
#define Cn 128
#define Tn 2048
#define Fn 5
#define Nn 640
#define TCHUNK 64
#define NCHUNK 32
#define BUFBYTES (Cn * TCHUNK * 2)   // 16 KB per bf16 buffer

typedef __attribute__((ext_vector_type(8))) short bf16x8;
typedef __attribute__((ext_vector_type(4))) short bf16x4;
typedef __attribute__((ext_vector_type(4))) float f32x4;

// round-to-nearest-even f32 -> bf16
__device__ __forceinline__ short f2bf(float f) {
    union { float f; unsigned u; } v; v.f = f;
    unsigned r = (v.u + 0x7fffu + ((v.u >> 16) & 1u)) >> 16;
    return (short)r;
}

// bf16 row = 128 B; XOR-swizzle rows across 16B slots (G4; conflicts 164K measured)
__device__ __forceinline__ int swz(int row, int bytecol) {
    return (row * 128 + bytecol) ^ ((row & 7) << 4);
}

__device__ __forceinline__ const float* pick_band(const float* d0, const float* d1,
                                                  const float* d2, const float* d3,
                                                  const float* d4, int f) {
    return (f == 0) ? d0 : (f == 1) ? d1 : (f == 2) ? d2 : (f == 3) ? d3 : d4;
}

// R9: 16-wave blocks (1024 threads) -> ~62% occupancy at grid=320 (k1's proven
// operating point), single-pass traffic. Wave grid 4x4, 32x32 Gram tile/wave.
// Raw s_barrier + lgkm-only drain; dual pf sets (vmcnt window spans phases).
// Output stripe written nontemporal so input stays L3-resident across replays.
__global__ __launch_bounds__(1024, 8)
void strg_mono(const float* __restrict__ d0, const float* __restrict__ d1,
               const float* __restrict__ d2, const float* __restrict__ d3,
               const float* __restrict__ d4, float* __restrict__ out)
{
    __shared__ __align__(16) char smem[Cn * Cn * 4];   // 64 KB: [0,32K) dbuf; epilogue f32 At
    __shared__ float S_lds[Cn], diag[Cn], mrow[Cn], ivrow[Cn], Dsum[Cn], dinv_s[Cn];

    const int tid = threadIdx.x;
    const int bfid = blockIdx.x;
    const int b = bfid / Fn;
    const int f = bfid - b * Fn;
    const float* src = pick_band(d0, d1, d2, d3, d4, f) + (size_t)b * Cn * Tn;

    if (tid < Cn) { S_lds[tid] = 0.0f; Dsum[tid] = 0.0f; }

    // staging: thread covers rows (tid>>4) + 64*i (i=0,1), 16 B at segment (tid&15)
    const int srow = tid >> 4;          // 0..63
    const int sseg = tid & 15;          // 0..15
    const float* tb0 = src + (size_t)srow * Tn + sseg * 4;

    // wave mapping: 16 waves in 4x4 grid, each owns a 32x32 tile of the Gram
    const int lane = tid & 63;
    const int w  = tid >> 6;            // 0..15
    const int wr = w >> 2;              // 0..3
    const int wc = w & 3;               // 0..3
    const int r0 = wr * 32;
    const int c0 = wc * 32;
    const int lg = lane >> 4;
    const int ll = lane & 15;

    f32x4 acc[2][2] = {};
    float psum[2] = {0.f, 0.f};
    float4 pfA[2], pfB[2];

    auto issueA = [&](int ch) {
        const float* cb = tb0 + ch * TCHUNK;
        #pragma unroll
        for (int i = 0; i < 2; ++i) pfA[i] = *(const float4*)(cb + (size_t)(i * 64) * Tn);
    };
    auto issueB = [&](int ch) {
        const float* cb = tb0 + ch * TCHUNK;
        #pragma unroll
        for (int i = 0; i < 2; ++i) pfB[i] = *(const float4*)(cb + (size_t)(i * 64) * Tn);
    };
    auto convA = [&](int buf) {
        char* base = smem + buf * BUFBYTES;
        #pragma unroll
        for (int i = 0; i < 2; ++i) {
            const int row = i * 64 + srow;
            float4 v = pfA[i];
            psum[i] += v.x + v.y + v.z + v.w;
            bf16x4 hh; hh[0] = f2bf(v.x); hh[1] = f2bf(v.y); hh[2] = f2bf(v.z); hh[3] = f2bf(v.w);
            *(bf16x4*)(base + swz(row, sseg * 8)) = hh;
        }
    };
    auto convB = [&](int buf) {
        char* base = smem + buf * BUFBYTES;
        #pragma unroll
        for (int i = 0; i < 2; ++i) {
            const int row = i * 64 + srow;
            float4 v = pfB[i];
            psum[i] += v.x + v.y + v.z + v.w;
            bf16x4 hh; hh[0] = f2bf(v.x); hh[1] = f2bf(v.y); hh[2] = f2bf(v.z); hh[3] = f2bf(v.w);
            *(bf16x4*)(base + swz(row, sseg * 8)) = hh;
        }
    };
    auto mfma_phase = [&](int buf) {
        const char* base = smem + buf * BUFBYTES;
        #pragma unroll
        for (int ks = 0; ks < 2; ++ks) {
            bf16x8 afr[2], bfr[2];
            #pragma unroll
            for (int m = 0; m < 2; ++m)
                afr[m] = *(const bf16x8*)(base + swz(r0 + m * 16 + ll, ks * 64 + lg * 16));
            #pragma unroll
            for (int n = 0; n < 2; ++n)
                bfr[n] = *(const bf16x8*)(base + swz(c0 + n * 16 + ll, ks * 64 + lg * 16));
            #pragma unroll
            for (int m = 0; m < 2; ++m)
                #pragma unroll
                for (int n = 0; n < 2; ++n)
                    acc[m][n] = __builtin_amdgcn_mfma_f32_16x16x32_bf16(afr[m], bfr[n], acc[m][n], 0, 0, 0);
        }
    };

    // prologue: chunk0 staged in buf0; chunk1 (B) and chunk2 (A) in flight
    issueA(0);
    issueB(1);
    convA(0);
    issueA(2);
    asm volatile("s_waitcnt lgkmcnt(0)" ::: "memory");
    __builtin_amdgcn_s_barrier();
    __builtin_amdgcn_sched_barrier(0);

    for (int k = 0; k < NCHUNK; k += 2) {
        convB(1);                                   // loads issued 1 full iter ago
        if (k + 3 < NCHUNK) issueB(k + 3);
        mfma_phase(0);
        asm volatile("s_waitcnt lgkmcnt(0)" ::: "memory");
        __builtin_amdgcn_s_barrier();               // raw: vmcnt lives across
        __builtin_amdgcn_sched_barrier(0);

        if (k + 2 < NCHUNK) {
            convA(0);
            if (k + 4 < NCHUNK) issueA(k + 4);
        }
        mfma_phase(1);
        asm volatile("s_waitcnt lgkmcnt(0)" ::: "memory");
        __builtin_amdgcn_s_barrier();
        __builtin_amdgcn_sched_barrier(0);
    }

    // ---- epilogue ----
    // row sums: psum[i] is a 16-lane partial for row srow + 64*i (16 aligned lanes)
    #pragma unroll
    for (int i = 0; i < 2; ++i) {
        float s = psum[i];
        s += __shfl_xor(s, 1);
        s += __shfl_xor(s, 2);
        s += __shfl_xor(s, 4);
        s += __shfl_xor(s, 8);
        if (ll == 0) S_lds[i * 64 + srow] = s;   // unique writer per row
    }

    #pragma unroll
    for (int m = 0; m < 2; ++m)
      #pragma unroll
      for (int n = 0; n < 2; ++n)
        #pragma unroll
        for (int e = 0; e < 4; ++e) {
            const int row = r0 + m * 16 + lg * 4 + e;
            const int col = c0 + n * 16 + ll;
            if (row == col) diag[row] = acc[m][n][e];
        }
    __syncthreads();

    if (tid < Cn) {
        const float S  = S_lds[tid];
        const float mu = S * (1.0f / Tn);
        float var = (diag[tid] - (float)Tn * mu * mu) * (1.0f / (Tn - 1));
        var = var < 0.f ? 0.f : var;
        const float sd = sqrtf(var);
        mrow[tid]  = mu;
        ivrow[tid] = 1.0f / (sd + 1e-8f);
        const size_t ofs = (size_t)Bn * Nn * Nn;
        __builtin_nontemporal_store(var, &out[ofs + (size_t)b * Nn + f * Cn + tid]);
        __builtin_nontemporal_store(var, &out[ofs + (size_t)Bn * Nn + ((size_t)b * Cn + tid) * Fn + f]);
    }
    __syncthreads();

    // a = 0.5*(spa + |corr|) -> LDS A-tile (reuse smem); accumulate row sums
    float* At = (float*)smem;
    {
        float mi[2][4], ii[2][4], mj[2], ij[2];
        #pragma unroll
        for (int m = 0; m < 2; ++m)
          #pragma unroll
          for (int e = 0; e < 4; ++e) {
              const int row = r0 + m * 16 + lg * 4 + e;
              mi[m][e] = mrow[row];
              ii[m][e] = ivrow[row];
          }
        #pragma unroll
        for (int n = 0; n < 2; ++n) {
            const int col = c0 + n * 16 + ll;
            mj[n] = mrow[col];
            ij[n] = ivrow[col];
        }
        const float inv = 1.0f / (Tn - 1);
        #pragma unroll
        for (int m = 0; m < 2; ++m)
          #pragma unroll
          for (int e = 0; e < 4; ++e) {
              const int row = r0 + m * 16 + lg * 4 + e;
              float s = 0.f;
              #pragma unroll
              for (int n = 0; n < 2; ++n) {
                  const int col = c0 + n * 16 + ll;
                  float c = fabsf((acc[m][n][e] - (float)Tn * mi[m][e] * mj[n])
                                  * ii[m][e] * ij[n] * inv);
                  c = (row == col) ? 1.0f : c;
                  const int d = row > col ? row - col : col - row;
                  const float spa = (d >= 1 && d <= 3) ? 1.0f : 0.0f;
                  const float a = 0.5f * (spa + c);
                  At[row * Cn + col] = a;
                  s += a;
              }
              s += __shfl_xor(s, 1);
              s += __shfl_xor(s, 2);
              s += __shfl_xor(s, 4);
              s += __shfl_xor(s, 8);
              if (ll == 0) atomicAdd(&Dsum[row], s);
          }
    }
    __syncthreads();

    if (tid < Cn) dinv_s[tid] = rsqrtf(Dsum[tid] + 1e-8f);
    __syncthreads();

    // write full 128x640 stripe of A_norm (coalesced float4, nontemporal)
    float* Ob = out + (size_t)b * Nn * Nn;
    const int fc = f * Cn;
    for (int e = 0; e < 20; ++e) {
        const int idx4 = e * 4096 + tid * 4;
        const int row = idx4 / Nn;
        const int col = idx4 - row * Nn;
        const int cl = col - fc;
        f32x4 v = {0.f, 0.f, 0.f, 0.f};
        if (cl >= 0 && cl < Cn) {
            const float dr = dinv_s[row];
            v[0] = dr * At[row * Cn + cl]     * dinv_s[cl];
            v[1] = dr * At[row * Cn + cl + 1] * dinv_s[cl + 1];
            v[2] = dr * At[row * Cn + cl + 2] * dinv_s[cl + 2];
            v[3] = dr * At[row * Cn + cl + 3] * dinv_s[cl + 3];
        }
        __builtin_nontemporal_store(v, (f32x4*)(Ob + (size_t)(fc + row) * Nn + col));
    }
}

extern "C" void kernel_launch(void* const* d_in, const int* in_sizes, int n_in,
                              void* d_out, int out_size, void* d_ws, size_t ws_size,
                              hipStream_t stream) {
    const float* d0 = (const float*)d_in[0];
    const float* d1 = (const float*)d_in[1];
    const float* d2 = (const float*)d_in[2];
    const float* d3 = (const float*)d_in[3];
    const float* d4 = (const float*)d_in[4];
    float* out = (float*)d_out;

    strg_mono<<<dim3(Bn * Fn), dim3(1024), 0, stream>>>(d0, d1, d2, d3, d4, out);
}